// Round 9
// baseline (153.227 us; speedup 1.0000x reference)
//
#include <hip/hip_runtime.h>

typedef __attribute__((ext_vector_type(8))) short bf16x8;
typedef __attribute__((ext_vector_type(4))) short bf16x4;
typedef __attribute__((ext_vector_type(4))) float f32x4;

#if __has_builtin(__builtin_amdgcn_exp2f)
#define EXP2(x) __builtin_amdgcn_exp2f(x)
#else
#define EXP2(x) exp2f(x)
#endif

__device__ __forceinline__ unsigned short f2bf(float f) {
    union { float f; unsigned int u; } v; v.f = f;
    unsigned int r = v.u + 0x7fffu + ((v.u >> 16) & 1u);
    return (unsigned short)(r >> 16);
}

__device__ __forceinline__ float asf(unsigned int u) {
    union { unsigned int u; float f; } v; v.u = u; return v.f;
}

// sqrt( (1/sqrt(32)) * log2(e) ) — baked into BOTH xqT operands so QK^T
// emerges pre-multiplied by scale*log2e: exp2(raw score) == softmax numerator.
#define QK_PRESCALE 0.50500983f

// ---------------------------------------------------------------------------
// Kernel 1: grouped 1x1 conv, 1024 blocks.
// R17: register-light restructure. The old body kept pv[32] + 64 hoisted
// float4 LDS reads live (spill suspect for the ~50us gap between total and
// attn+rooflines). New: j4-outer loop loads 4 inputs/iter (no pv array),
// identical FP summation order, #pragma unroll 2, __launch_bounds__(256,4)
// (live ~50 regs, cap 128 -> no spill possible).
// Writes xqT [h][n][i] (bf16, i contiguous, PRE-SCALED)  -> QK MFMA operands
//        xv  [h][i][n] (bf16, n contiguous)              -> PV A-op (V=elu(x))
// ---------------------------------------------------------------------------
__global__ __launch_bounds__(256, 4) void conv_kernel(
    const float* __restrict__ points, const float* __restrict__ conv_w,
    const float* __restrict__ conv_b,
    unsigned short* __restrict__ xqT, unsigned short* __restrict__ xv)
{
    __shared__ float w[1024];
    const int h  = blockIdx.x >> 6;   // 16 heads
    const int nc = blockIdx.x & 63;   // 64 n-chunks of 64
    const int g  = h & 7;
    const int tid = threadIdx.x;
    const float* wg = conv_w + g * 1024;
    for (int k = tid; k < 1024; k += 256) w[k] = wg[k];
    __syncthreads();
    const int n  = nc * 64 + (tid & 63);
    const int ig = tid >> 6;          // wave id -> channels [ig*8, ig*8+8)
    const float* p = points + (size_t)h * 32 * 4096 + n;

    float out[8];
#pragma unroll
    for (int ii = 0; ii < 8; ++ii) out[ii] = conv_b[g * 32 + ig * 8 + ii];

    const float4* w4base = (const float4*)(w + ig * 8 * 32);  // [ii][j4]
#pragma unroll 2
    for (int j4 = 0; j4 < 8; ++j4) {
        float pv0 = p[(size_t)(j4 * 4 + 0) * 4096];
        float pv1 = p[(size_t)(j4 * 4 + 1) * 4096];
        float pv2 = p[(size_t)(j4 * 4 + 2) * 4096];
        float pv3 = p[(size_t)(j4 * 4 + 3) * 4096];
#pragma unroll
        for (int ii = 0; ii < 8; ++ii) {
            float4 ww = w4base[ii * 8 + j4];   // ds_read_b128, broadcast
            out[ii] += ww.x * pv0 + ww.y * pv1 + ww.z * pv2 + ww.w * pv3;
        }
    }

    unsigned short tq[8];
#pragma unroll
    for (int ii = 0; ii < 8; ++ii) tq[ii] = f2bf(out[ii] * QK_PRESCALE);
    *(bf16x8*)(xqT + ((size_t)h * 4096 + n) * 32 + ig * 8) = *(bf16x8*)tq;
#pragma unroll
    for (int ii = 0; ii < 8; ++ii) {
        float x = out[ii];
        float e = x > 0.f ? x : (__expf(x) - 1.f);   // elu
        xv[((size_t)h * 32 + ig * 8 + ii) * 4096 + n] = f2bf(e);
    }
}

// ---------------------------------------------------------------------------
// Kernel 2: flash attention. R16 body (passed, 86.4us): single barrier per
// 128-key chunk via V double-buffer, P in-register via permlane32/16_swap,
// K frags direct global->reg 8+8 double-buffered, GN-stats fusion epilogue.
// R17 adds only s_setprio(1)/(0) around the PV MFMA cluster (T5): 4
// independent blocks/CU sit at different phases, so boosting the MFMA-
// entering wave helps the CU scheduler. Register-neutral.
// ---------------------------------------------------------------------------
#define VSTR 136   // 128 + 8 pad shorts

#if __has_builtin(__builtin_amdgcn_cvt_pk_bf16_f32)
typedef __attribute__((ext_vector_type(2))) __bf16 bf16x2v;
__device__ __forceinline__ bf16x4 exp_pack(f32x4 sc, float& lsum) {
    float e0 = EXP2(sc[0]), e1 = EXP2(sc[1]);
    float e2 = EXP2(sc[2]), e3 = EXP2(sc[3]);
    lsum += (e0 + e1) + (e2 + e3);
    union { bf16x2v v[2]; bf16x4 s; } u;
    u.v[0] = __builtin_amdgcn_cvt_pk_bf16_f32(e0, e1);
    u.v[1] = __builtin_amdgcn_cvt_pk_bf16_f32(e2, e3);
    return u.s;
}
#else
__device__ __forceinline__ bf16x4 exp_pack(f32x4 sc, float& lsum) {
    union { float f; unsigned int u; } e0, e1, e2, e3;
    e0.f = EXP2(sc[0]); e1.f = EXP2(sc[1]); e2.f = EXP2(sc[2]); e3.f = EXP2(sc[3]);
    unsigned int t0 = e0.u & 0xffff0000u, t1 = e1.u & 0xffff0000u;
    unsigned int t2 = e2.u & 0xffff0000u, t3 = e3.u & 0xffff0000u;
    lsum += (asf(t0) + asf(t1)) + (asf(t2) + asf(t3));
    union { unsigned int d[2]; bf16x4 v; } pk;
    pk.d[0] = (t0 >> 16) | t1;
    pk.d[1] = (t2 >> 16) | t3;
    return pk.v;
}
#endif

// One 128-key chunk against V buffer VH: store staged V, ONE barrier,
// prefetch next V (regs) + next K frags (KP), compute 8 x 16-key steps from
// current K frags (KU). pf wraps to 0 on the last chunk (harmless).
#define CHUNK(C0, KU, KP, VH)                                                  \
    {                                                                          \
        *(bf16x8*)((VH) + vi * VSTR + vn)      = va;                           \
        *(bf16x8*)((VH) + vi * VSTR + vn + 64) = vb;                           \
        __syncthreads();                                                       \
        const int pfb = ((C0) + 128) & 4095;                                   \
        va = *(const bf16x8*)(vbase + (size_t)vi * 4096 + pfb + vn);           \
        vb = *(const bf16x8*)(vbase + (size_t)vi * 4096 + pfb + vn + 64);      \
        _Pragma("unroll")                                                      \
        for (int s8 = 0; s8 < 8; ++s8)                                         \
            KP[s8] = *(const bf16x8*)(kfp + (size_t)(pfb + s8 * 16) * 32);     \
        _Pragma("unroll")                                                      \
        for (int sub = 0; sub < 2; ++sub) {                                    \
            union { bf16x4 v; unsigned int d[2]; } E[4];                       \
            _Pragma("unroll")                                                  \
            for (int s = 0; s < 4; ++s) {                                      \
                f32x4 sc = __builtin_amdgcn_mfma_f32_16x16x32_bf16(            \
                    KU[sub * 4 + s], qfrag, (f32x4){0.f, 0.f, 0.f, 0.f},       \
                    0, 0, 0);                                                  \
                E[s].v = exp_pack(sc, lsum);                                   \
            }                                                                  \
            union { unsigned int d[4]; bf16x8 v; } F0, F1;                     \
            _Pragma("unroll")                                                  \
            for (int p = 0; p < 2; ++p) {                                      \
                unsigned int a0 = E[0].d[p], b0 = E[1].d[p];                   \
                asm("v_permlane32_swap_b32 %0, %1" : "+v"(a0), "+v"(b0));      \
                asm("v_permlane16_swap_b32 %0, %1" : "+v"(a0), "+v"(b0));      \
                F0.d[p] = a0; F0.d[2 + p] = b0;                                \
                unsigned int a1 = E[2].d[p], b1 = E[3].d[p];                   \
                asm("v_permlane32_swap_b32 %0, %1" : "+v"(a1), "+v"(b1));      \
                asm("v_permlane16_swap_b32 %0, %1" : "+v"(a1), "+v"(b1));      \
                F1.d[p] = a1; F1.d[2 + p] = b1;                                \
            }                                                                  \
            __builtin_amdgcn_s_setprio(1);                                     \
            _Pragma("unroll")                                                  \
            for (int ng = 0; ng < 2; ++ng) {                                   \
                bf16x8 pfrag = ng ? F1.v : F0.v;                               \
                const int col = sub * 64 + ng * 32 + quad * 8;                 \
                bf16x8 v0 = *(const bf16x8*)((VH) + l15 * VSTR + col);         \
                bf16x8 v1 = *(const bf16x8*)((VH) + (16 + l15) * VSTR + col);  \
                acc0 = __builtin_amdgcn_mfma_f32_16x16x32_bf16(v0, pfrag,      \
                                                               acc0, 0, 0, 0); \
                acc1 = __builtin_amdgcn_mfma_f32_16x16x32_bf16(v1, pfrag,      \
                                                               acc1, 0, 0, 0); \
            }                                                                  \
            __builtin_amdgcn_s_setprio(0);                                     \
        }                                                                      \
    }

__global__ __launch_bounds__(256, 4) void attn_kernel(
    const unsigned short* __restrict__ xqT,
    const unsigned short* __restrict__ xv,
    const float* __restrict__ points,
    float* __restrict__ z,
    float* __restrict__ part)
{
    __shared__ unsigned short Vt[2][32 * VSTR];   // double-buffered, 17408 B

    const int h  = blockIdx.y;
    const int b = h >> 3, g = h & 7;
    const int tid = threadIdx.x;
    const int wv = tid >> 6, lane = tid & 63;
    const int quad = lane >> 4, l15 = lane & 15;

    const int m = blockIdx.x * 64 + wv * 16 + l15;   // this lane's query col

    const unsigned short* kbase = xqT + (size_t)h * 4096 * 32;
    const unsigned short* vbase = xv  + (size_t)h * 32 * 4096;

    // Q fragment (B-operand): col=l15, k=quad*8+j
    const bf16x8 qfrag = *(const bf16x8*)(kbase + (size_t)m * 32 + quad * 8);

    f32x4 acc0 = {0.f, 0.f, 0.f, 0.f};   // O rows i = 0..15
    f32x4 acc1 = {0.f, 0.f, 0.f, 0.f};   // O rows i = 16..31
    float lsum = 0.f;

    const int vi = tid >> 3, vn = (tid & 7) * 8;   // V staging: [i][n], 2 cols
    unsigned short* Vt0 = &Vt[0][0];
    unsigned short* Vt1 = &Vt[1][0];

    // per-lane K-fragment base: row l15, cols quad*8..+8 (A-operand K^T).
    // For key block n: frag = kfp + n*32.  Wave's 8 frags of a chunk are a
    // permutation of one aligned 1KB block -> fully coalesced dwordx4 loads.
    const unsigned short* kfp = kbase + (size_t)l15 * 32 + quad * 8;

    // V staging prefetch regs (chunk 0)
    const unsigned short* vptr = vbase + (size_t)vi * 4096 + vn;
    bf16x8 va = *(const bf16x8*)vptr;
    bf16x8 vb = *(const bf16x8*)(vptr + 64);

    // K fragment double buffer (chunk 0 into kA)
    bf16x8 kA[8], kB[8];
#pragma unroll
    for (int s8 = 0; s8 < 8; ++s8)
        kA[s8] = *(const bf16x8*)(kfp + (size_t)(s8 * 16) * 32);

    for (int n0 = 0; n0 < 4096; n0 += 256) {
        CHUNK(n0,       kA, kB, Vt0);   // even chunk -> buffer 0
        CHUNK(n0 + 128, kB, kA, Vt1);   // odd chunk  -> buffer 1
    }

    // denominator: sum partial l over the 4 quads sharing column m
    lsum += __shfl_xor(lsum, 16, 64);
    lsum += __shfl_xor(lsum, 32, 64);
    const float inv = 1.f / lsum;

    const float* pb = points + (size_t)b * 256 * 4096;
    float* zb = z + (size_t)b * 256 * 4096;
    float sA[8], ssA[8];
#pragma unroll
    for (int half = 0; half < 2; ++half) {
        f32x4 a = half ? acc1 : acc0;
#pragma unroll
        for (int r = 0; r < 4; ++r) {
            int i = half * 16 + quad * 4 + r;             // C/D row mapping
            size_t off = (size_t)(i * 8 + g) * 4096 + m;  // channel shuffle
            float zv = a[r] * inv + pb[off];              // + identity
            zb[off] = zv;
            // GN group of channel i*8+g is i (g<8): quad-reduce over 16 m-lanes
            float s = zv, ss = zv * zv;
#pragma unroll
            for (int d = 1; d < 16; d <<= 1) {
                s  += __shfl_xor(s, d, 64);
                ss += __shfl_xor(ss, d, 64);
            }
            sA[half * 4 + r] = s; ssA[half * 4 + r] = ss;
        }
    }
    // block-level combine through LDS (reuse Vt; all waves are past their
    // last Vt read only after this barrier)
    __syncthreads();
    float2* Ls = (float2*)&Vt[0][0];    // [wv][i]  128 float2 = 1 KB
    if (l15 == 0) {
#pragma unroll
        for (int k = 0; k < 8; ++k) {
            int i = (k >> 2) * 16 + quad * 4 + (k & 3);
            Ls[wv * 32 + i] = make_float2(sA[k], ssA[k]);
        }
    }
    __syncthreads();
    if (tid < 32) {
        float2 p0 = Ls[tid], p1 = Ls[32 + tid], p2 = Ls[64 + tid], p3 = Ls[96 + tid];
        float s  = p0.x + p1.x + p2.x + p3.x;
        float ss = p0.y + p1.y + p2.y + p3.y;
        // part[slot][sc][512], slot = b*32+i, position = g*64+bx: unique.
        size_t base = ((size_t)(b * 32 + tid)) * 1024 + (size_t)g * 64 + blockIdx.x;
        part[base]       = s;
        part[base + 512] = ss;
    }
}

// ---------------------------------------------------------------------------
// Kernel 3: GroupNorm apply, in place on d_out. All 256 threads of a block
// share one channel (chg = blockIdx.x>>2), hence one GN group: the block
// first reduces its group's 512 (s,ss) partials (4 KB, L2-resident), then
// applies the affine normalization to its 256 float4.
// ---------------------------------------------------------------------------
__global__ __launch_bounds__(256) void gn_apply(float* __restrict__ z,
                                                const float* __restrict__ part,
                                                const float* __restrict__ gw,
                                                const float* __restrict__ gb)
{
    const int tid = threadIdx.x;
    const int idx = blockIdx.x * 256 + tid;  // float4 index
    const int chg = blockIdx.x >> 2;         // global channel b*256+ch
    const int grp = chg >> 3;                // group slot = b*32 + ch/8
    const int ch  = chg & 255;

    const float* pp = part + (size_t)grp * 1024;
    float s  = pp[tid]       + pp[tid + 256];
    float ss = pp[512 + tid] + pp[768 + tid];
#pragma unroll
    for (int off = 32; off > 0; off >>= 1) {
        s  += __shfl_down(s, off, 64);
        ss += __shfl_down(ss, off, 64);
    }
    __shared__ float red[8];
    if ((tid & 63) == 0) { red[(tid >> 6) * 2] = s; red[(tid >> 6) * 2 + 1] = ss; }
    __syncthreads();
    s  = red[0] + red[2] + red[4] + red[6];
    ss = red[1] + red[3] + red[5] + red[7];

    const float mean = s * (1.f / 32768.f);
    const float var  = ss * (1.f / 32768.f) - mean * mean;
    const float rstd = rsqrtf(var + 1e-5f);
    const float w  = gw[ch] * rstd;
    const float bb = gb[ch] - mean * w;
    float4* p = (float4*)z;
    float4 v = p[idx];
    v.x = v.x * w + bb; v.y = v.y * w + bb;
    v.z = v.z * w + bb; v.w = v.w * w + bb;
    p[idx] = v;
}

extern "C" void kernel_launch(void* const* d_in, const int* in_sizes, int n_in,
                              void* d_out, int out_size, void* d_ws, size_t ws_size,
                              hipStream_t stream)
{
    const float* points = (const float*)d_in[0];
    const float* conv_w = (const float*)d_in[1];
    const float* conv_b = (const float*)d_in[2];
    const float* gn_w   = (const float*)d_in[3];
    const float* gn_b   = (const float*)d_in[4];
    float* out = (float*)d_out;
    char* ws = (char*)d_ws;
    unsigned short* xqT = (unsigned short*)ws;                             // 4 MB
    unsigned short* xv  = (unsigned short*)(ws + (size_t)4 * 1024 * 1024); // 4 MB
    float* part = (float*)(ws + (size_t)8 * 1024 * 1024);                  // 256 KB

    conv_kernel<<<1024, 256, 0, stream>>>(points, conv_w, conv_b, xqT, xv);
    attn_kernel<<<dim3(64, 16), 256, 0, stream>>>(xqT, xv, points, out, part);
    gn_apply<<<2048, 256, 0, stream>>>(out, part, gn_w, gn_b);
}

// Round 10
// 150.917 us; speedup vs baseline: 1.0153x; 1.0153x over previous
//
#include <hip/hip_runtime.h>

typedef __attribute__((ext_vector_type(8))) short bf16x8;
typedef __attribute__((ext_vector_type(4))) short bf16x4;
typedef __attribute__((ext_vector_type(4))) float f32x4;

#if __has_builtin(__builtin_amdgcn_exp2f)
#define EXP2(x) __builtin_amdgcn_exp2f(x)
#else
#define EXP2(x) exp2f(x)
#endif

__device__ __forceinline__ unsigned short f2bf(float f) {
    union { float f; unsigned int u; } v; v.f = f;
    unsigned int r = v.u + 0x7fffu + ((v.u >> 16) & 1u);
    return (unsigned short)(r >> 16);
}

__device__ __forceinline__ float asf(unsigned int u) {
    union { unsigned int u; float f; } v; v.u = u; return v.f;
}

// sqrt( (1/sqrt(32)) * log2(e) ) — baked into BOTH xqT operands so QK^T
// emerges pre-multiplied by scale*log2e: exp2(raw score) == softmax numerator.
#define QK_PRESCALE 0.50500983f

// ---------------------------------------------------------------------------
// Kernel 1: grouped 1x1 conv, 1024 blocks. Register-light j4-outer form
// (R17, perf-neutral vs R9 form but lower live set).
// Writes xqT [h][n][i] (bf16, i contiguous, PRE-SCALED)  -> QK MFMA operands
//        xv  [h][i][n] (bf16, n contiguous)              -> PV A-op (V=elu(x))
// ---------------------------------------------------------------------------
__global__ __launch_bounds__(256, 4) void conv_kernel(
    const float* __restrict__ points, const float* __restrict__ conv_w,
    const float* __restrict__ conv_b,
    unsigned short* __restrict__ xqT, unsigned short* __restrict__ xv)
{
    __shared__ float w[1024];
    const int h  = blockIdx.x >> 6;   // 16 heads
    const int nc = blockIdx.x & 63;   // 64 n-chunks of 64
    const int g  = h & 7;
    const int tid = threadIdx.x;
    const float* wg = conv_w + g * 1024;
    for (int k = tid; k < 1024; k += 256) w[k] = wg[k];
    __syncthreads();
    const int n  = nc * 64 + (tid & 63);
    const int ig = tid >> 6;          // wave id -> channels [ig*8, ig*8+8)
    const float* p = points + (size_t)h * 32 * 4096 + n;

    float out[8];
#pragma unroll
    for (int ii = 0; ii < 8; ++ii) out[ii] = conv_b[g * 32 + ig * 8 + ii];

    const float4* w4base = (const float4*)(w + ig * 8 * 32);  // [ii][j4]
#pragma unroll 2
    for (int j4 = 0; j4 < 8; ++j4) {
        float pv0 = p[(size_t)(j4 * 4 + 0) * 4096];
        float pv1 = p[(size_t)(j4 * 4 + 1) * 4096];
        float pv2 = p[(size_t)(j4 * 4 + 2) * 4096];
        float pv3 = p[(size_t)(j4 * 4 + 3) * 4096];
#pragma unroll
        for (int ii = 0; ii < 8; ++ii) {
            float4 ww = w4base[ii * 8 + j4];   // ds_read_b128, broadcast
            out[ii] += ww.x * pv0 + ww.y * pv1 + ww.z * pv2 + ww.w * pv3;
        }
    }

    unsigned short tq[8];
#pragma unroll
    for (int ii = 0; ii < 8; ++ii) tq[ii] = f2bf(out[ii] * QK_PRESCALE);
    *(bf16x8*)(xqT + ((size_t)h * 4096 + n) * 32 + ig * 8) = *(bf16x8*)tq;
#pragma unroll
    for (int ii = 0; ii < 8; ++ii) {
        float x = out[ii];
        float e = x > 0.f ? x : (__expf(x) - 1.f);   // elu
        xv[((size_t)h * 32 + ig * 8 + ii) * 4096 + n] = f2bf(e);
    }
}

// ---------------------------------------------------------------------------
// Kernel 2: flash attention. R18 = R16 body (best passing, 86.4us: single
// barrier per 128-key chunk via V double-buffer, P in-register via
// permlane32/16_swap, K frags direct global->reg 8+8 double-buffered,
// GN-stats fusion epilogue) with:
//   - setprio REVERTED (R17: +3.6us, occupancy 35.7->30.6 — hurts barrier-
//     synced lockstep blocks, consistent with T5 catalog).
//   - lsum split into 4 independent partials lsq[0..3] (one per score step
//     s): kills the 32-add loop-carried chain per chunk (~4 cyc x 32 of
//     exposed latency at 4 waves/SIMD). Summation-order change only.
// ---------------------------------------------------------------------------
#define VSTR 136   // 128 + 8 pad shorts

#if __has_builtin(__builtin_amdgcn_cvt_pk_bf16_f32)
typedef __attribute__((ext_vector_type(2))) __bf16 bf16x2v;
__device__ __forceinline__ bf16x4 exp_pack(f32x4 sc, float& lsum) {
    float e0 = EXP2(sc[0]), e1 = EXP2(sc[1]);
    float e2 = EXP2(sc[2]), e3 = EXP2(sc[3]);
    lsum += (e0 + e1) + (e2 + e3);
    union { bf16x2v v[2]; bf16x4 s; } u;
    u.v[0] = __builtin_amdgcn_cvt_pk_bf16_f32(e0, e1);
    u.v[1] = __builtin_amdgcn_cvt_pk_bf16_f32(e2, e3);
    return u.s;
}
#else
__device__ __forceinline__ bf16x4 exp_pack(f32x4 sc, float& lsum) {
    union { float f; unsigned int u; } e0, e1, e2, e3;
    e0.f = EXP2(sc[0]); e1.f = EXP2(sc[1]); e2.f = EXP2(sc[2]); e3.f = EXP2(sc[3]);
    unsigned int t0 = e0.u & 0xffff0000u, t1 = e1.u & 0xffff0000u;
    unsigned int t2 = e2.u & 0xffff0000u, t3 = e3.u & 0xffff0000u;
    lsum += (asf(t0) + asf(t1)) + (asf(t2) + asf(t3));
    union { unsigned int d[2]; bf16x4 v; } pk;
    pk.d[0] = (t0 >> 16) | t1;
    pk.d[1] = (t2 >> 16) | t3;
    return pk.v;
}
#endif

// One 128-key chunk against V buffer VH: store staged V, ONE barrier,
// prefetch next V (regs) + next K frags (KP), compute 8 x 16-key steps from
// current K frags (KU). pf wraps to 0 on the last chunk (harmless).
#define CHUNK(C0, KU, KP, VH)                                                  \
    {                                                                          \
        *(bf16x8*)((VH) + vi * VSTR + vn)      = va;                           \
        *(bf16x8*)((VH) + vi * VSTR + vn + 64) = vb;                           \
        __syncthreads();                                                       \
        const int pfb = ((C0) + 128) & 4095;                                   \
        va = *(const bf16x8*)(vbase + (size_t)vi * 4096 + pfb + vn);           \
        vb = *(const bf16x8*)(vbase + (size_t)vi * 4096 + pfb + vn + 64);      \
        _Pragma("unroll")                                                      \
        for (int s8 = 0; s8 < 8; ++s8)                                         \
            KP[s8] = *(const bf16x8*)(kfp + (size_t)(pfb + s8 * 16) * 32);     \
        _Pragma("unroll")                                                      \
        for (int sub = 0; sub < 2; ++sub) {                                    \
            union { bf16x4 v; unsigned int d[2]; } E[4];                       \
            _Pragma("unroll")                                                  \
            for (int s = 0; s < 4; ++s) {                                      \
                f32x4 sc = __builtin_amdgcn_mfma_f32_16x16x32_bf16(            \
                    KU[sub * 4 + s], qfrag, (f32x4){0.f, 0.f, 0.f, 0.f},       \
                    0, 0, 0);                                                  \
                E[s].v = exp_pack(sc, lsq[s]);                                 \
            }                                                                  \
            union { unsigned int d[4]; bf16x8 v; } F0, F1;                     \
            _Pragma("unroll")                                                  \
            for (int p = 0; p < 2; ++p) {                                      \
                unsigned int a0 = E[0].d[p], b0 = E[1].d[p];                   \
                asm("v_permlane32_swap_b32 %0, %1" : "+v"(a0), "+v"(b0));      \
                asm("v_permlane16_swap_b32 %0, %1" : "+v"(a0), "+v"(b0));      \
                F0.d[p] = a0; F0.d[2 + p] = b0;                                \
                unsigned int a1 = E[2].d[p], b1 = E[3].d[p];                   \
                asm("v_permlane32_swap_b32 %0, %1" : "+v"(a1), "+v"(b1));      \
                asm("v_permlane16_swap_b32 %0, %1" : "+v"(a1), "+v"(b1));      \
                F1.d[p] = a1; F1.d[2 + p] = b1;                                \
            }                                                                  \
            _Pragma("unroll")                                                  \
            for (int ng = 0; ng < 2; ++ng) {                                   \
                bf16x8 pfrag = ng ? F1.v : F0.v;                               \
                const int col = sub * 64 + ng * 32 + quad * 8;                 \
                bf16x8 v0 = *(const bf16x8*)((VH) + l15 * VSTR + col);         \
                bf16x8 v1 = *(const bf16x8*)((VH) + (16 + l15) * VSTR + col);  \
                acc0 = __builtin_amdgcn_mfma_f32_16x16x32_bf16(v0, pfrag,      \
                                                               acc0, 0, 0, 0); \
                acc1 = __builtin_amdgcn_mfma_f32_16x16x32_bf16(v1, pfrag,      \
                                                               acc1, 0, 0, 0); \
            }                                                                  \
        }                                                                      \
    }

__global__ __launch_bounds__(256, 4) void attn_kernel(
    const unsigned short* __restrict__ xqT,
    const unsigned short* __restrict__ xv,
    const float* __restrict__ points,
    float* __restrict__ z,
    float* __restrict__ part)
{
    __shared__ unsigned short Vt[2][32 * VSTR];   // double-buffered, 17408 B

    const int h  = blockIdx.y;
    const int b = h >> 3, g = h & 7;
    const int tid = threadIdx.x;
    const int wv = tid >> 6, lane = tid & 63;
    const int quad = lane >> 4, l15 = lane & 15;

    const int m = blockIdx.x * 64 + wv * 16 + l15;   // this lane's query col

    const unsigned short* kbase = xqT + (size_t)h * 4096 * 32;
    const unsigned short* vbase = xv  + (size_t)h * 32 * 4096;

    // Q fragment (B-operand): col=l15, k=quad*8+j
    const bf16x8 qfrag = *(const bf16x8*)(kbase + (size_t)m * 32 + quad * 8);

    f32x4 acc0 = {0.f, 0.f, 0.f, 0.f};   // O rows i = 0..15
    f32x4 acc1 = {0.f, 0.f, 0.f, 0.f};   // O rows i = 16..31
    float lsq[4] = {0.f, 0.f, 0.f, 0.f}; // per-score-step partial denominators

    const int vi = tid >> 3, vn = (tid & 7) * 8;   // V staging: [i][n], 2 cols
    unsigned short* Vt0 = &Vt[0][0];
    unsigned short* Vt1 = &Vt[1][0];

    // per-lane K-fragment base: row l15, cols quad*8..+8 (A-operand K^T).
    // For key block n: frag = kfp + n*32.  Wave's 8 frags of a chunk are a
    // permutation of one aligned 1KB block -> fully coalesced dwordx4 loads.
    const unsigned short* kfp = kbase + (size_t)l15 * 32 + quad * 8;

    // V staging prefetch regs (chunk 0)
    const unsigned short* vptr = vbase + (size_t)vi * 4096 + vn;
    bf16x8 va = *(const bf16x8*)vptr;
    bf16x8 vb = *(const bf16x8*)(vptr + 64);

    // K fragment double buffer (chunk 0 into kA)
    bf16x8 kA[8], kB[8];
#pragma unroll
    for (int s8 = 0; s8 < 8; ++s8)
        kA[s8] = *(const bf16x8*)(kfp + (size_t)(s8 * 16) * 32);

    for (int n0 = 0; n0 < 4096; n0 += 256) {
        CHUNK(n0,       kA, kB, Vt0);   // even chunk -> buffer 0
        CHUNK(n0 + 128, kB, kA, Vt1);   // odd chunk  -> buffer 1
    }

    // denominator: merge the 4 partials, then sum over the 4 quads sharing m
    float lsum = (lsq[0] + lsq[1]) + (lsq[2] + lsq[3]);
    lsum += __shfl_xor(lsum, 16, 64);
    lsum += __shfl_xor(lsum, 32, 64);
    const float inv = 1.f / lsum;

    const float* pb = points + (size_t)b * 256 * 4096;
    float* zb = z + (size_t)b * 256 * 4096;
    float sA[8], ssA[8];
#pragma unroll
    for (int half = 0; half < 2; ++half) {
        f32x4 a = half ? acc1 : acc0;
#pragma unroll
        for (int r = 0; r < 4; ++r) {
            int i = half * 16 + quad * 4 + r;             // C/D row mapping
            size_t off = (size_t)(i * 8 + g) * 4096 + m;  // channel shuffle
            float zv = a[r] * inv + pb[off];              // + identity
            zb[off] = zv;
            // GN group of channel i*8+g is i (g<8): quad-reduce over 16 m-lanes
            float s = zv, ss = zv * zv;
#pragma unroll
            for (int d = 1; d < 16; d <<= 1) {
                s  += __shfl_xor(s, d, 64);
                ss += __shfl_xor(ss, d, 64);
            }
            sA[half * 4 + r] = s; ssA[half * 4 + r] = ss;
        }
    }
    // block-level combine through LDS (reuse Vt; all waves are past their
    // last Vt read only after this barrier)
    __syncthreads();
    float2* Ls = (float2*)&Vt[0][0];    // [wv][i]  128 float2 = 1 KB
    if (l15 == 0) {
#pragma unroll
        for (int k = 0; k < 8; ++k) {
            int i = (k >> 2) * 16 + quad * 4 + (k & 3);
            Ls[wv * 32 + i] = make_float2(sA[k], ssA[k]);
        }
    }
    __syncthreads();
    if (tid < 32) {
        float2 p0 = Ls[tid], p1 = Ls[32 + tid], p2 = Ls[64 + tid], p3 = Ls[96 + tid];
        float s  = p0.x + p1.x + p2.x + p3.x;
        float ss = p0.y + p1.y + p2.y + p3.y;
        // part[slot][sc][512], slot = b*32+i, position = g*64+bx: unique.
        size_t base = ((size_t)(b * 32 + tid)) * 1024 + (size_t)g * 64 + blockIdx.x;
        part[base]       = s;
        part[base + 512] = ss;
    }
}

// ---------------------------------------------------------------------------
// Kernel 3: GroupNorm apply, in place on d_out. All 256 threads of a block
// share one channel (chg = blockIdx.x>>2), hence one GN group: the block
// first reduces its group's 512 (s,ss) partials (4 KB, L2-resident), then
// applies the affine normalization to its 256 float4.
// ---------------------------------------------------------------------------
__global__ __launch_bounds__(256) void gn_apply(float* __restrict__ z,
                                                const float* __restrict__ part,
                                                const float* __restrict__ gw,
                                                const float* __restrict__ gb)
{
    const int tid = threadIdx.x;
    const int idx = blockIdx.x * 256 + tid;  // float4 index
    const int chg = blockIdx.x >> 2;         // global channel b*256+ch
    const int grp = chg >> 3;                // group slot = b*32 + ch/8
    const int ch  = chg & 255;

    const float* pp = part + (size_t)grp * 1024;
    float s  = pp[tid]       + pp[tid + 256];
    float ss = pp[512 + tid] + pp[768 + tid];
#pragma unroll
    for (int off = 32; off > 0; off >>= 1) {
        s  += __shfl_down(s, off, 64);
        ss += __shfl_down(ss, off, 64);
    }
    __shared__ float red[8];
    if ((tid & 63) == 0) { red[(tid >> 6) * 2] = s; red[(tid >> 6) * 2 + 1] = ss; }
    __syncthreads();
    s  = red[0] + red[2] + red[4] + red[6];
    ss = red[1] + red[3] + red[5] + red[7];

    const float mean = s * (1.f / 32768.f);
    const float var  = ss * (1.f / 32768.f) - mean * mean;
    const float rstd = rsqrtf(var + 1e-5f);
    const float w  = gw[ch] * rstd;
    const float bb = gb[ch] - mean * w;
    float4* p = (float4*)z;
    float4 v = p[idx];
    v.x = v.x * w + bb; v.y = v.y * w + bb;
    v.z = v.z * w + bb; v.w = v.w * w + bb;
    p[idx] = v;
}

extern "C" void kernel_launch(void* const* d_in, const int* in_sizes, int n_in,
                              void* d_out, int out_size, void* d_ws, size_t ws_size,
                              hipStream_t stream)
{
    const float* points = (const float*)d_in[0];
    const float* conv_w = (const float*)d_in[1];
    const float* conv_b = (const float*)d_in[2];
    const float* gn_w   = (const float*)d_in[3];
    const float* gn_b   = (const float*)d_in[4];
    float* out = (float*)d_out;
    char* ws = (char*)d_ws;
    unsigned short* xqT = (unsigned short*)ws;                             // 4 MB
    unsigned short* xv  = (unsigned short*)(ws + (size_t)4 * 1024 * 1024); // 4 MB
    float* part = (float*)(ws + (size_t)8 * 1024 * 1024);                  // 256 KB

    conv_kernel<<<1024, 256, 0, stream>>>(points, conv_w, conv_b, xqT, xv);
    attn_kernel<<<dim3(64, 16), 256, 0, stream>>>(xqT, xv, points, out, part);
    gn_apply<<<2048, 256, 0, stream>>>(out, part, gn_w, gn_b);
}

// Round 11
// 149.022 us; speedup vs baseline: 1.0282x; 1.0127x over previous
//
#include <hip/hip_runtime.h>

typedef __attribute__((ext_vector_type(8))) short bf16x8;
typedef __attribute__((ext_vector_type(4))) short bf16x4;
typedef __attribute__((ext_vector_type(4))) float f32x4;

#if __has_builtin(__builtin_amdgcn_exp2f)
#define EXP2(x) __builtin_amdgcn_exp2f(x)
#else
#define EXP2(x) exp2f(x)
#endif

__device__ __forceinline__ unsigned short f2bf(float f) {
    union { float f; unsigned int u; } v; v.f = f;
    unsigned int r = v.u + 0x7fffu + ((v.u >> 16) & 1u);
    return (unsigned short)(r >> 16);
}

__device__ __forceinline__ float asf(unsigned int u) {
    union { unsigned int u; float f; } v; v.u = u; return v.f;
}

// sqrt( (1/sqrt(32)) * log2(e) ) — baked into BOTH xqT operands so QK^T
// emerges pre-multiplied by scale*log2e: exp2(raw score) == softmax numerator.
#define QK_PRESCALE 0.50500983f

// ---------------------------------------------------------------------------
// Kernel 1: grouped 1x1 conv, 1024 blocks. Register-light j4-outer form.
// Writes xqT [h][n][i] (bf16, i contiguous, PRE-SCALED)  -> QK MFMA operands
//        xv  [h][i][n] (bf16, n contiguous)              -> PV A-op (V=elu(x))
// ---------------------------------------------------------------------------
__global__ __launch_bounds__(256, 4) void conv_kernel(
    const float* __restrict__ points, const float* __restrict__ conv_w,
    const float* __restrict__ conv_b,
    unsigned short* __restrict__ xqT, unsigned short* __restrict__ xv)
{
    __shared__ float w[1024];
    const int h  = blockIdx.x >> 6;   // 16 heads
    const int nc = blockIdx.x & 63;   // 64 n-chunks of 64
    const int g  = h & 7;
    const int tid = threadIdx.x;
    const float* wg = conv_w + g * 1024;
    for (int k = tid; k < 1024; k += 256) w[k] = wg[k];
    __syncthreads();
    const int n  = nc * 64 + (tid & 63);
    const int ig = tid >> 6;          // wave id -> channels [ig*8, ig*8+8)
    const float* p = points + (size_t)h * 32 * 4096 + n;

    float out[8];
#pragma unroll
    for (int ii = 0; ii < 8; ++ii) out[ii] = conv_b[g * 32 + ig * 8 + ii];

    const float4* w4base = (const float4*)(w + ig * 8 * 32);  // [ii][j4]
#pragma unroll 2
    for (int j4 = 0; j4 < 8; ++j4) {
        float pv0 = p[(size_t)(j4 * 4 + 0) * 4096];
        float pv1 = p[(size_t)(j4 * 4 + 1) * 4096];
        float pv2 = p[(size_t)(j4 * 4 + 2) * 4096];
        float pv3 = p[(size_t)(j4 * 4 + 3) * 4096];
#pragma unroll
        for (int ii = 0; ii < 8; ++ii) {
            float4 ww = w4base[ii * 8 + j4];   // ds_read_b128, broadcast
            out[ii] += ww.x * pv0 + ww.y * pv1 + ww.z * pv2 + ww.w * pv3;
        }
    }

    unsigned short tq[8];
#pragma unroll
    for (int ii = 0; ii < 8; ++ii) tq[ii] = f2bf(out[ii] * QK_PRESCALE);
    *(bf16x8*)(xqT + ((size_t)h * 4096 + n) * 32 + ig * 8) = *(bf16x8*)tq;
#pragma unroll
    for (int ii = 0; ii < 8; ++ii) {
        float x = out[ii];
        float e = x > 0.f ? x : (__expf(x) - 1.f);   // elu
        xv[((size_t)h * 32 + ig * 8 + ii) * 4096 + n] = f2bf(e);
    }
}

// ---------------------------------------------------------------------------
// Kernel 2: flash attention. R19 = R16/R18 body (best passing, 86.4us) with
// the softmax denominator moved onto the MFMA pipe: one extra
// mfma(ones, pfrag, accL) per P-fragment (A = all-ones -> every output row
// = column sum of P). Deletes the 24 lsum VALU adds per chunk (VALU is the
// loaded pipe at ~48% vs MFMA 16%), shortens the exp_pack chain (pure
// exp+cvt now), and kills the final quad shfl_xor reduce (one MFMA sums a
// full 32-key window across all 4 quads jointly -> accL[0] is the complete
// denominator per query column). Denominator now sums bf16-rounded P —
// exactly what PV multiplies. Register-neutral (~+4 VGPR).
// ---------------------------------------------------------------------------
#define VSTR 136   // 128 + 8 pad shorts

#if __has_builtin(__builtin_amdgcn_cvt_pk_bf16_f32)
typedef __attribute__((ext_vector_type(2))) __bf16 bf16x2v;
__device__ __forceinline__ bf16x4 exp_pack(f32x4 sc) {
    float e0 = EXP2(sc[0]), e1 = EXP2(sc[1]);
    float e2 = EXP2(sc[2]), e3 = EXP2(sc[3]);
    union { bf16x2v v[2]; bf16x4 s; } u;
    u.v[0] = __builtin_amdgcn_cvt_pk_bf16_f32(e0, e1);
    u.v[1] = __builtin_amdgcn_cvt_pk_bf16_f32(e2, e3);
    return u.s;
}
#else
__device__ __forceinline__ bf16x4 exp_pack(f32x4 sc) {
    union { float f; unsigned int u; } e0, e1, e2, e3;
    e0.f = EXP2(sc[0]); e1.f = EXP2(sc[1]); e2.f = EXP2(sc[2]); e3.f = EXP2(sc[3]);
    unsigned int t0 = e0.u & 0xffff0000u, t1 = e1.u & 0xffff0000u;
    unsigned int t2 = e2.u & 0xffff0000u, t3 = e3.u & 0xffff0000u;
    union { unsigned int d[2]; bf16x4 v; } pk;
    pk.d[0] = (t0 >> 16) | t1;
    pk.d[1] = (t2 >> 16) | t3;
    return pk.v;
}
#endif

// One 128-key chunk against V buffer VH: store staged V, ONE barrier,
// prefetch next V (regs) + next K frags (KP), compute 8 x 16-key steps from
// current K frags (KU). pf wraps to 0 on the last chunk (harmless).
#define CHUNK(C0, KU, KP, VH)                                                  \
    {                                                                          \
        *(bf16x8*)((VH) + vi * VSTR + vn)      = va;                           \
        *(bf16x8*)((VH) + vi * VSTR + vn + 64) = vb;                           \
        __syncthreads();                                                       \
        const int pfb = ((C0) + 128) & 4095;                                   \
        va = *(const bf16x8*)(vbase + (size_t)vi * 4096 + pfb + vn);           \
        vb = *(const bf16x8*)(vbase + (size_t)vi * 4096 + pfb + vn + 64);      \
        _Pragma("unroll")                                                      \
        for (int s8 = 0; s8 < 8; ++s8)                                         \
            KP[s8] = *(const bf16x8*)(kfp + (size_t)(pfb + s8 * 16) * 32);     \
        _Pragma("unroll")                                                      \
        for (int sub = 0; sub < 2; ++sub) {                                    \
            union { bf16x4 v; unsigned int d[2]; } E[4];                       \
            _Pragma("unroll")                                                  \
            for (int s = 0; s < 4; ++s) {                                      \
                f32x4 sc = __builtin_amdgcn_mfma_f32_16x16x32_bf16(            \
                    KU[sub * 4 + s], qfrag, (f32x4){0.f, 0.f, 0.f, 0.f},       \
                    0, 0, 0);                                                  \
                E[s].v = exp_pack(sc);                                         \
            }                                                                  \
            union { unsigned int d[4]; bf16x8 v; } F0, F1;                     \
            _Pragma("unroll")                                                  \
            for (int p = 0; p < 2; ++p) {                                      \
                unsigned int a0 = E[0].d[p], b0 = E[1].d[p];                   \
                asm("v_permlane32_swap_b32 %0, %1" : "+v"(a0), "+v"(b0));      \
                asm("v_permlane16_swap_b32 %0, %1" : "+v"(a0), "+v"(b0));      \
                F0.d[p] = a0; F0.d[2 + p] = b0;                                \
                unsigned int a1 = E[2].d[p], b1 = E[3].d[p];                   \
                asm("v_permlane32_swap_b32 %0, %1" : "+v"(a1), "+v"(b1));      \
                asm("v_permlane16_swap_b32 %0, %1" : "+v"(a1), "+v"(b1));      \
                F1.d[p] = a1; F1.d[2 + p] = b1;                                \
            }                                                                  \
            _Pragma("unroll")                                                  \
            for (int ng = 0; ng < 2; ++ng) {                                   \
                bf16x8 pfrag = ng ? F1.v : F0.v;                               \
                const int col = sub * 64 + ng * 32 + quad * 8;                 \
                bf16x8 v0 = *(const bf16x8*)((VH) + l15 * VSTR + col);         \
                bf16x8 v1 = *(const bf16x8*)((VH) + (16 + l15) * VSTR + col);  \
                acc0 = __builtin_amdgcn_mfma_f32_16x16x32_bf16(v0, pfrag,      \
                                                               acc0, 0, 0, 0); \
                acc1 = __builtin_amdgcn_mfma_f32_16x16x32_bf16(v1, pfrag,      \
                                                               acc1, 0, 0, 0); \
                accL = __builtin_amdgcn_mfma_f32_16x16x32_bf16(ones, pfrag,    \
                                                               accL, 0, 0, 0); \
            }                                                                  \
        }                                                                      \
    }

__global__ __launch_bounds__(256, 4) void attn_kernel(
    const unsigned short* __restrict__ xqT,
    const unsigned short* __restrict__ xv,
    const float* __restrict__ points,
    float* __restrict__ z,
    float* __restrict__ part)
{
    __shared__ unsigned short Vt[2][32 * VSTR];   // double-buffered, 17408 B

    const int h  = blockIdx.y;
    const int b = h >> 3, g = h & 7;
    const int tid = threadIdx.x;
    const int wv = tid >> 6, lane = tid & 63;
    const int quad = lane >> 4, l15 = lane & 15;

    const int m = blockIdx.x * 64 + wv * 16 + l15;   // this lane's query col

    const unsigned short* kbase = xqT + (size_t)h * 4096 * 32;
    const unsigned short* vbase = xv  + (size_t)h * 32 * 4096;

    // Q fragment (B-operand): col=l15, k=quad*8+j
    const bf16x8 qfrag = *(const bf16x8*)(kbase + (size_t)m * 32 + quad * 8);

    f32x4 acc0 = {0.f, 0.f, 0.f, 0.f};   // O rows i = 0..15
    f32x4 acc1 = {0.f, 0.f, 0.f, 0.f};   // O rows i = 16..31
    f32x4 accL = {0.f, 0.f, 0.f, 0.f};   // softmax denominator (ones-row MFMA)
    const short one_bf = (short)0x3f80;  // bf16 1.0
    const bf16x8 ones = {one_bf, one_bf, one_bf, one_bf,
                         one_bf, one_bf, one_bf, one_bf};

    const int vi = tid >> 3, vn = (tid & 7) * 8;   // V staging: [i][n], 2 cols
    unsigned short* Vt0 = &Vt[0][0];
    unsigned short* Vt1 = &Vt[1][0];

    // per-lane K-fragment base: row l15, cols quad*8..+8 (A-operand K^T).
    // For key block n: frag = kfp + n*32.  Wave's 8 frags of a chunk are a
    // permutation of one aligned 1KB block -> fully coalesced dwordx4 loads.
    const unsigned short* kfp = kbase + (size_t)l15 * 32 + quad * 8;

    // V staging prefetch regs (chunk 0)
    const unsigned short* vptr = vbase + (size_t)vi * 4096 + vn;
    bf16x8 va = *(const bf16x8*)vptr;
    bf16x8 vb = *(const bf16x8*)(vptr + 64);

    // K fragment double buffer (chunk 0 into kA)
    bf16x8 kA[8], kB[8];
#pragma unroll
    for (int s8 = 0; s8 < 8; ++s8)
        kA[s8] = *(const bf16x8*)(kfp + (size_t)(s8 * 16) * 32);

    for (int n0 = 0; n0 < 4096; n0 += 256) {
        CHUNK(n0,       kA, kB, Vt0);   // even chunk -> buffer 0
        CHUNK(n0 + 128, kB, kA, Vt1);   // odd chunk  -> buffer 1
    }

    // denominator: every output row of the ones-MFMA equals the full column
    // sum (each call jointly sums all 4 quads' 32-key window), so accL[0]
    // is already the complete denominator for query column m — no shfl.
    const float inv = 1.f / accL[0];

    const float* pb = points + (size_t)b * 256 * 4096;
    float* zb = z + (size_t)b * 256 * 4096;
    float sA[8], ssA[8];
#pragma unroll
    for (int half = 0; half < 2; ++half) {
        f32x4 a = half ? acc1 : acc0;
#pragma unroll
        for (int r = 0; r < 4; ++r) {
            int i = half * 16 + quad * 4 + r;             // C/D row mapping
            size_t off = (size_t)(i * 8 + g) * 4096 + m;  // channel shuffle
            float zv = a[r] * inv + pb[off];              // + identity
            zb[off] = zv;
            // GN group of channel i*8+g is i (g<8): quad-reduce over 16 m-lanes
            float s = zv, ss = zv * zv;
#pragma unroll
            for (int d = 1; d < 16; d <<= 1) {
                s  += __shfl_xor(s, d, 64);
                ss += __shfl_xor(ss, d, 64);
            }
            sA[half * 4 + r] = s; ssA[half * 4 + r] = ss;
        }
    }
    // block-level combine through LDS (reuse Vt; all waves are past their
    // last Vt read only after this barrier)
    __syncthreads();
    float2* Ls = (float2*)&Vt[0][0];    // [wv][i]  128 float2 = 1 KB
    if (l15 == 0) {
#pragma unroll
        for (int k = 0; k < 8; ++k) {
            int i = (k >> 2) * 16 + quad * 4 + (k & 3);
            Ls[wv * 32 + i] = make_float2(sA[k], ssA[k]);
        }
    }
    __syncthreads();
    if (tid < 32) {
        float2 p0 = Ls[tid], p1 = Ls[32 + tid], p2 = Ls[64 + tid], p3 = Ls[96 + tid];
        float s  = p0.x + p1.x + p2.x + p3.x;
        float ss = p0.y + p1.y + p2.y + p3.y;
        // part[slot][sc][512], slot = b*32+i, position = g*64+bx: unique.
        size_t base = ((size_t)(b * 32 + tid)) * 1024 + (size_t)g * 64 + blockIdx.x;
        part[base]       = s;
        part[base + 512] = ss;
    }
}

// ---------------------------------------------------------------------------
// Kernel 3: GroupNorm apply, in place on d_out. All 256 threads of a block
// share one channel (chg = blockIdx.x>>2), hence one GN group: the block
// first reduces its group's 512 (s,ss) partials (4 KB, L2-resident), then
// applies the affine normalization to its 256 float4.
// ---------------------------------------------------------------------------
__global__ __launch_bounds__(256) void gn_apply(float* __restrict__ z,
                                                const float* __restrict__ part,
                                                const float* __restrict__ gw,
                                                const float* __restrict__ gb)
{
    const int tid = threadIdx.x;
    const int idx = blockIdx.x * 256 + tid;  // float4 index
    const int chg = blockIdx.x >> 2;         // global channel b*256+ch
    const int grp = chg >> 3;                // group slot = b*32 + ch/8
    const int ch  = chg & 255;

    const float* pp = part + (size_t)grp * 1024;
    float s  = pp[tid]       + pp[tid + 256];
    float ss = pp[512 + tid] + pp[768 + tid];
#pragma unroll
    for (int off = 32; off > 0; off >>= 1) {
        s  += __shfl_down(s, off, 64);
        ss += __shfl_down(ss, off, 64);
    }
    __shared__ float red[8];
    if ((tid & 63) == 0) { red[(tid >> 6) * 2] = s; red[(tid >> 6) * 2 + 1] = ss; }
    __syncthreads();
    s  = red[0] + red[2] + red[4] + red[6];
    ss = red[1] + red[3] + red[5] + red[7];

    const float mean = s * (1.f / 32768.f);
    const float var  = ss * (1.f / 32768.f) - mean * mean;
    const float rstd = rsqrtf(var + 1e-5f);
    const float w  = gw[ch] * rstd;
    const float bb = gb[ch] - mean * w;
    float4* p = (float4*)z;
    float4 v = p[idx];
    v.x = v.x * w + bb; v.y = v.y * w + bb;
    v.z = v.z * w + bb; v.w = v.w * w + bb;
    p[idx] = v;
}

extern "C" void kernel_launch(void* const* d_in, const int* in_sizes, int n_in,
                              void* d_out, int out_size, void* d_ws, size_t ws_size,
                              hipStream_t stream)
{
    const float* points = (const float*)d_in[0];
    const float* conv_w = (const float*)d_in[1];
    const float* conv_b = (const float*)d_in[2];
    const float* gn_w   = (const float*)d_in[3];
    const float* gn_b   = (const float*)d_in[4];
    float* out = (float*)d_out;
    char* ws = (char*)d_ws;
    unsigned short* xqT = (unsigned short*)ws;                             // 4 MB
    unsigned short* xv  = (unsigned short*)(ws + (size_t)4 * 1024 * 1024); // 4 MB
    float* part = (float*)(ws + (size_t)8 * 1024 * 1024);                  // 256 KB

    conv_kernel<<<1024, 256, 0, stream>>>(points, conv_w, conv_b, xqT, xv);
    attn_kernel<<<dim3(64, 16), 256, 0, stream>>>(xqT, xv, points, out, part);
    gn_apply<<<2048, 256, 0, stream>>>(out, part, gn_w, gn_b);
}